// Round 12
// baseline (116.945 us; speedup 1.0000x reference)
//
#include <hip/hip_runtime.h>

// SegmentMM: out[i] = A[i] (1x64) @ B_eff[segA[i]] (64x64), N=131072, K=M=64, S=128.
// segment_id_A sorted; B_eff[segB[j]] = B[j].
//
// Round-9: rounds 6/8 proved the compiler re-serializes C-level load bursts
// (VGPR_Count=60 vs planned ~200; 1.3 TB/s; MfmaUtil 0.75%). Fix is structural:
//  - A loads = 16x inline-asm global_load_dwordx4 per wave, issued back-to-back
//    (asm volatile cannot be reordered or register-minimized), one explicit
//    s_waitcnt vmcnt(0) + sched_barrier(0) before consumption (rule #18).
//  - B[seg] staged to LDS per block (16KB cooperative f32x4 copy, one barrier),
//    then per-wave ds_read+cvt into 8 pinned bf16 fragments. A-burst is issued
//    BEFORE the B copy, so compiler vmcnt waits only over-wait (asm loads
//    older) -> correct, single merged HBM stall per wave.
//  - MFMA operand order / output indexing identical to round-8 (passed,
//    absmax 0.25): acc = mfma(Bfrag, Afrag, acc); lane stores one dwordx4.
//  - Non-uniform blocks (seg boundary inside 256 rows, <=127/512) take the
//    round-8 slow path (no barrier - block-uniform branch).

typedef float f32x4 __attribute__((ext_vector_type(4)));
typedef short s16x8 __attribute__((ext_vector_type(8)));

#define RPB 256  // rows per block (4 waves x 64)
#define RPW 64   // rows per wave

__global__ void build_inv_kernel(const int* __restrict__ segB, int* __restrict__ inv, int S) {
    int j = threadIdx.x + blockIdx.x * blockDim.x;
    if (j < S) inv[segB[j]] = j;
}

__device__ __forceinline__ short f2bf(float f) {  // RNE f32 -> bf16 bits
    unsigned u = __builtin_bit_cast(unsigned, f);
    u += 0x7fffu + ((u >> 16) & 1u);
    return (short)(u >> 16);
}

// back-to-back vector loads the scheduler cannot touch
#define GL(d, p, o) \
    asm volatile("global_load_dwordx4 %0, %1, off offset:" #o : "=v"(d) : "v"(p))
#define GLM(d, p, o) /* last load: memory clobber fences later B-copy loads */ \
    asm volatile("global_load_dwordx4 %0, %1, off offset:" #o : "=v"(d) : "v"(p) : "memory")

__global__ __launch_bounds__(256, 2) void segmm_mfma(
        const float* __restrict__ A,     // [N,64]
        const float* __restrict__ B,     // [S,64,64]
        const int*   __restrict__ segA,  // [N] sorted
        const int*   __restrict__ inv,   // [S]
        float*       __restrict__ out,   // [N,64]
        int nrows) {
    __shared__ __align__(16) float Blds[4096];  // one 64x64 f32 segment matrix

    const int tid  = threadIdx.x;
    const int lane = tid & 63;
    const int n16  = lane & 15;   // output row within 16 / B col within 16
    const int kg   = lane >> 4;   // 0..3
    const int wid  = tid >> 6;    // wave in block

    const int br0 = __builtin_amdgcn_readfirstlane((int)blockIdx.x * RPB);
    if (br0 >= nrows) return;
    const bool whole = (br0 + RPB <= nrows);
    const int sFirst = __builtin_amdgcn_readfirstlane(segA[br0]);
    const int sLast  = whole ? __builtin_amdgcn_readfirstlane(segA[br0 + RPB - 1]) : -1;

    if (whole && sFirst == sLast) {
        // ================= fast path: block-uniform segment =================
        const int j = __builtin_amdgcn_readfirstlane(inv[sFirst]);
        const int r0 = br0 + wid * RPW;

        // --- A burst: 16 asm dwordx4, issued before anything else ---
        const float* abase = A + (size_t)(r0 + n16) * 64 + kg * 8;
        const float* p0 = abase;
        const float* p1 = abase + 1024;
        const float* p2 = abase + 2048;
        const float* p3 = abase + 3072;
        f32x4 av0, av1, av2, av3, av4, av5, av6, av7,
              av8, av9, av10, av11, av12, av13, av14, av15;
        GL(av0,  p0, 0); GL(av1,  p0, 16); GL(av2,  p0, 128); GL(av3,  p0, 144);
        GL(av4,  p1, 0); GL(av5,  p1, 16); GL(av6,  p1, 128); GL(av7,  p1, 144);
        GL(av8,  p2, 0); GL(av9,  p2, 16); GL(av10, p2, 128); GL(av11, p2, 144);
        GL(av12, p3, 0); GL(av13, p3, 16); GL(av14, p3, 128); GLM(av15, p3, 144);

        // --- cooperative B copy to LDS (16KB; compiler waits over-wait on
        //     the older asm loads -> correct) ---
        {
            const f32x4* __restrict__ bsrc = (const f32x4*)(B + (size_t)j * 4096);
            f32x4* bdst = (f32x4*)Blds;
            #pragma unroll
            for (int it = 0; it < 4; ++it)
                bdst[tid + it * 256] = bsrc[tid + it * 256];
        }
        __syncthreads();

        // --- B fragments from LDS (amortized over 64 rows/wave) ---
        s16x8 bfr[4][2];
        #pragma unroll
        for (int ct = 0; ct < 4; ++ct)
            #pragma unroll
            for (int ks = 0; ks < 2; ++ks)
                #pragma unroll
                for (int i = 0; i < 8; ++i)
                    bfr[ct][ks][i] = f2bf(Blds[(size_t)(kg * 8 + i + ks * 32) * 64 + ct * 16 + n16]);
        asm volatile("" : "+v"(bfr[0][0]), "+v"(bfr[0][1]), "+v"(bfr[1][0]), "+v"(bfr[1][1]),
                          "+v"(bfr[2][0]), "+v"(bfr[2][1]), "+v"(bfr[3][0]), "+v"(bfr[3][1]));

        // --- A data is drained (barrier emitted vmcnt(0)); fence anyway ---
        asm volatile("s_waitcnt vmcnt(0)" ::: "memory");
        __builtin_amdgcn_sched_barrier(0);

        // --- cvt A -> bf16 fragments ---
        s16x8 af[4][2];
        #define CVT_T(t, vA, vB, vC, vD) do {                         \
            _Pragma("unroll")                                         \
            for (int i = 0; i < 4; ++i) {                             \
                af[t][0][i]     = f2bf(vA[i]);                        \
                af[t][0][i + 4] = f2bf(vB[i]);                        \
                af[t][1][i]     = f2bf(vC[i]);                        \
                af[t][1][i + 4] = f2bf(vD[i]);                        \
            } } while (0)
        CVT_T(0, av0,  av1,  av2,  av3);
        CVT_T(1, av4,  av5,  av6,  av7);
        CVT_T(2, av8,  av9,  av10, av11);
        CVT_T(3, av12, av13, av14, av15);
        #undef CVT_T

        // --- 32 MFMA + coalesced dwordx4 stores ---
        #pragma unroll
        for (int t = 0; t < 4; ++t) {
            #pragma unroll
            for (int ct = 0; ct < 4; ++ct) {
                f32x4 acc = {0.f, 0.f, 0.f, 0.f};
                acc = __builtin_amdgcn_mfma_f32_16x16x32_bf16(bfr[ct][0], af[t][0], acc, 0, 0, 0);
                acc = __builtin_amdgcn_mfma_f32_16x16x32_bf16(bfr[ct][1], af[t][1], acc, 0, 0, 0);
                *(f32x4*)(out + (size_t)(r0 + t * 16 + n16) * 64 + ct * 16 + kg * 4) = acc;
            }
        }
    } else {
        // ================= slow path (round-8, verified) =================
        const int r0 = br0 + wid * RPW;
        if (r0 >= nrows) return;
        int j_cur = -1;
        s16x8 bfr[4][2];
        for (int t = 0; t < RPW / 16; ++t) {
            const int rt = r0 + 16 * t;
            if (rt >= nrows) break;
            const bool full = (rt + 16 <= nrows);
            const int sa = __builtin_amdgcn_readfirstlane(segA[rt]);
            const int sb = full ? __builtin_amdgcn_readfirstlane(segA[rt + 15]) : -1;

            if (full && sa == sb) {
                const int j = __builtin_amdgcn_readfirstlane(inv[sa]);
                if (j != j_cur) {
                    j_cur = j;
                    const float* __restrict__ bbase = B + (size_t)j * 4096 + n16;
                    #pragma unroll
                    for (int ct = 0; ct < 4; ++ct)
                        #pragma unroll
                        for (int ks = 0; ks < 2; ++ks) {
                            float tmp[8];
                            #pragma unroll
                            for (int i = 0; i < 8; ++i)
                                tmp[i] = bbase[(size_t)(kg * 8 + i + ks * 32) * 64 + ct * 16];
                            #pragma unroll
                            for (int i = 0; i < 8; ++i)
                                bfr[ct][ks][i] = f2bf(tmp[i]);
                        }
                }
                const float* __restrict__ ap = A + (size_t)(rt + n16) * 64 + kg * 8;
                s16x8 af0, af1;
                {
                    f32x4 lo  = *(const f32x4*)(ap);
                    f32x4 hi  = *(const f32x4*)(ap + 4);
                    f32x4 lo2 = *(const f32x4*)(ap + 32);
                    f32x4 hi2 = *(const f32x4*)(ap + 36);
                    #pragma unroll
                    for (int i = 0; i < 4; ++i) {
                        af0[i]     = f2bf(lo[i]);
                        af0[i + 4] = f2bf(hi[i]);
                        af1[i]     = f2bf(lo2[i]);
                        af1[i + 4] = f2bf(hi2[i]);
                    }
                }
                #pragma unroll
                for (int ct = 0; ct < 4; ++ct) {
                    f32x4 acc = {0.f, 0.f, 0.f, 0.f};
                    acc = __builtin_amdgcn_mfma_f32_16x16x32_bf16(bfr[ct][0], af0, acc, 0, 0, 0);
                    acc = __builtin_amdgcn_mfma_f32_16x16x32_bf16(bfr[ct][1], af1, acc, 0, 0, 0);
                    *(f32x4*)(out + (size_t)(rt + n16) * 64 + ct * 16 + kg * 4) = acc;
                }
            } else {
                const int rEnd = full ? rt + 16 : nrows;
                for (int r = rt; r < rEnd; ++r) {
                    const int s = __builtin_amdgcn_readfirstlane(segA[r]);
                    const int j = __builtin_amdgcn_readfirstlane(inv[s]);
                    const float* __restrict__ ap = A + (size_t)r * 64;
                    const float* __restrict__ bp = B + (size_t)j * 4096 + lane;
                    float a0 = 0.f, a1 = 0.f, a2 = 0.f, a3 = 0.f;
                    #pragma unroll
                    for (int k = 0; k < 64; k += 4) {
                        a0 = fmaf(ap[k + 0], bp[(size_t)(k + 0) * 64], a0);
                        a1 = fmaf(ap[k + 1], bp[(size_t)(k + 1) * 64], a1);
                        a2 = fmaf(ap[k + 2], bp[(size_t)(k + 2) * 64], a2);
                        a3 = fmaf(ap[k + 3], bp[(size_t)(k + 3) * 64], a3);
                    }
                    out[(size_t)r * 64 + lane] = (a0 + a1) + (a2 + a3);
                }
                j_cur = -1;
            }
        }
    }
}

extern "C" void kernel_launch(void* const* d_in, const int* in_sizes, int n_in,
                              void* d_out, int out_size, void* d_ws, size_t ws_size,
                              hipStream_t stream) {
    const float* A    = (const float*)d_in[0];
    const float* B    = (const float*)d_in[1];
    const int*   segA = (const int*)d_in[2];
    const int*   segB = (const int*)d_in[3];
    float*       out  = (float*)d_out;
    int*         inv  = (int*)d_ws;   // S ints of scratch

    const int K = 64;
    const int N = in_sizes[0] / K;    // 131072
    const int S = in_sizes[3];        // 128

    build_inv_kernel<<<(S + 127) / 128, 128, 0, stream>>>(segB, inv, S);

    int blocks = (N + RPB - 1) / RPB;  // 512
    segmm_mfma<<<blocks, 256, 0, stream>>>(A, B, segA, inv, out, N);
}

// Round 13
// 92.853 us; speedup vs baseline: 1.2595x; 1.2595x over previous
//
#include <hip/hip_runtime.h>

// SegmentMM: out[i] = A[i] (1x64) @ B_eff[segA[i]] (64x64), N=131072, K=M=64, S=128.
// segment_id_A sorted; B_eff[segB[j]] = B[j].
//
// Round-13: kill the boundary tail. Rounds 5/8/12 all landed ~44-54us with
// OccupancyPercent ~5%: fast-path blocks finish in ~5us, then ~127 boundary
// blocks grind a per-row fp32 loop for ~40us on a near-empty machine. The
// per-row path is gone. Unified multi-pass wave structure:
//  - per wave (64 rows): asm A-burst (16x global_load_dwordx4, held live =
//    round-12 proven), load 64 per-row segment ids, then loop over the
//    wave's distinct segments (<=2 for this data; correct for any count):
//    load B-frags for segment s (coalesced dwords, L2-resident), 32 MFMA
//    over all 4 tiles, stores PREDICATED on sid[row]==s.
//  - next segment = wave-min over sids > s (shfl_xor butterfly). No LDS,
//    no barriers, no divergent-latency slow path.
//  - MFMA operand order / D-layout identical to rounds 8/12 (passed,
//    absmax 0.25): acc = mfma(Bfrag, Afrag, acc); lane stores one dwordx4,
//    lanes {n,n+16,n+32,n+48} cover full 64B lines.

typedef float f32x4 __attribute__((ext_vector_type(4)));
typedef short s16x8 __attribute__((ext_vector_type(8)));

#define RPW 64   // rows per wave (4 MFMA tiles)
#define WPB 4    // waves per block

__global__ void build_inv_kernel(const int* __restrict__ segB, int* __restrict__ inv, int S) {
    int j = threadIdx.x + blockIdx.x * blockDim.x;
    if (j < S) inv[segB[j]] = j;
}

__device__ __forceinline__ short f2bf(float f) {  // RNE f32 -> bf16 bits
    unsigned u = __builtin_bit_cast(unsigned, f);
    u += 0x7fffu + ((u >> 16) & 1u);
    return (short)(u >> 16);
}

__device__ __forceinline__ int wave_min_u(int v) {  // wave-wide min, uniform result
    #pragma unroll
    for (int m = 32; m; m >>= 1) {
        int o = __shfl_xor(v, m, 64);
        v = o < v ? o : v;
    }
    return __builtin_amdgcn_readfirstlane(v);
}

// back-to-back vector loads the scheduler cannot reorder or register-minimize
#define GL(d, p, o) \
    asm volatile("global_load_dwordx4 %0, %1, off offset:" #o : "=v"(d) : "v"(p))
#define GLM(d, p, o) \
    asm volatile("global_load_dwordx4 %0, %1, off offset:" #o : "=v"(d) : "v"(p) : "memory")

__global__ __launch_bounds__(256, 2) void segmm_mfma(
        const float* __restrict__ A,     // [N,64]
        const float* __restrict__ B,     // [S,64,64]
        const int*   __restrict__ segA,  // [N] sorted
        const int*   __restrict__ inv,   // [S]
        float*       __restrict__ out,   // [N,64]
        int nrows) {
    const int lane = threadIdx.x & 63;
    const int n16  = lane & 15;   // output row within tile / B col within 16
    const int kg   = lane >> 4;   // 0..3

    const int w  = blockIdx.x * WPB + (threadIdx.x >> 6);
    const int r0 = __builtin_amdgcn_readfirstlane(w * RPW);
    if (r0 >= nrows) return;

    if (r0 + RPW <= nrows) {
        // ---------------- main path: 64 full rows, any segment layout ----------------
        // A burst: 16 asm dwordx4 covering this wave's 64 rows (16KB in flight).
        const float* abase = A + (size_t)(r0 + n16) * 64 + kg * 8;
        const float* p0 = abase;
        const float* p1 = abase + 1024;
        const float* p2 = abase + 2048;
        const float* p3 = abase + 3072;
        f32x4 av0, av1, av2, av3, av4, av5, av6, av7,
              av8, av9, av10, av11, av12, av13, av14, av15;
        GL(av0,  p0, 0); GL(av1,  p0, 16); GL(av2,  p0, 128); GL(av3,  p0, 144);
        GL(av4,  p1, 0); GL(av5,  p1, 16); GL(av6,  p1, 128); GL(av7,  p1, 144);
        GL(av8,  p2, 0); GL(av9,  p2, 16); GL(av10, p2, 128); GL(av11, p2, 144);
        GL(av12, p3, 0); GL(av13, p3, 16); GL(av14, p3, 128); GLM(av15, p3, 144);

        // Per-row segment ids for the 4 rows this lane stores (t=0..3).
        const int sid0 = segA[r0 + 0 * 16 + n16];
        const int sid1 = segA[r0 + 1 * 16 + n16];
        const int sid2 = segA[r0 + 2 * 16 + n16];
        const int sid3 = segA[r0 + 3 * 16 + n16];

        int c0 = sid0 < sid1 ? sid0 : sid1;
        int c1 = sid2 < sid3 ? sid2 : sid3;
        int s  = wave_min_u(c0 < c1 ? c0 : c1);   // first (smallest) segment

        // Drain A burst + sid loads, then convert A once (registers persist).
        asm volatile("s_waitcnt vmcnt(0)" ::: "memory");
        __builtin_amdgcn_sched_barrier(0);

        s16x8 af[4][2];
        #define CVT_T(t, vA, vB, vC, vD) do {                         \
            _Pragma("unroll")                                         \
            for (int i = 0; i < 4; ++i) {                             \
                af[t][0][i]     = f2bf(vA[i]);                        \
                af[t][0][i + 4] = f2bf(vB[i]);                        \
                af[t][1][i]     = f2bf(vC[i]);                        \
                af[t][1][i + 4] = f2bf(vD[i]);                        \
            } } while (0)
        CVT_T(0, av0,  av1,  av2,  av3);
        CVT_T(1, av4,  av5,  av6,  av7);
        CVT_T(2, av8,  av9,  av10, av11);
        CVT_T(3, av12, av13, av14, av15);
        #undef CVT_T

        // Loop over distinct segments present in this wave's rows (usually 1,
        // 2 at a boundary; s strictly increases -> terminates).
        while (true) {
            const int j = __builtin_amdgcn_readfirstlane(inv[s]);

            // B fragments for segment j: 64 coalesced dword loads + cvt.
            const float* __restrict__ bbase = B + (size_t)j * 4096 + n16;
            float bt[4][2][8];
            #pragma unroll
            for (int ct = 0; ct < 4; ++ct)
                #pragma unroll
                for (int ks = 0; ks < 2; ++ks)
                    #pragma unroll
                    for (int i = 0; i < 8; ++i)
                        bt[ct][ks][i] = bbase[(size_t)(kg * 8 + i + ks * 32) * 64 + ct * 16];
            s16x8 bfr[4][2];
            #pragma unroll
            for (int ct = 0; ct < 4; ++ct)
                #pragma unroll
                for (int ks = 0; ks < 2; ++ks)
                    #pragma unroll
                    for (int i = 0; i < 8; ++i)
                        bfr[ct][ks][i] = f2bf(bt[ct][ks][i]);

            // 32 MFMA; stores predicated on the row's segment matching s.
            #define TILE(t, sidt) do {                                                 \
                const bool st_ = (sidt == s);                                          \
                _Pragma("unroll")                                                      \
                for (int ct = 0; ct < 4; ++ct) {                                       \
                    f32x4 acc = {0.f, 0.f, 0.f, 0.f};                                  \
                    acc = __builtin_amdgcn_mfma_f32_16x16x32_bf16(bfr[ct][0], af[t][0], acc, 0, 0, 0); \
                    acc = __builtin_amdgcn_mfma_f32_16x16x32_bf16(bfr[ct][1], af[t][1], acc, 0, 0, 0); \
                    if (st_)                                                           \
                        *(f32x4*)(out + (size_t)(r0 + t * 16 + n16) * 64 + ct * 16 + kg * 4) = acc; \
                } } while (0)
            TILE(0, sid0);
            TILE(1, sid1);
            TILE(2, sid2);
            TILE(3, sid3);
            #undef TILE

            // Next distinct segment: min over sids strictly greater than s.
            int cand = 0x7fffffff;
            if (sid0 > s && sid0 < cand) cand = sid0;
            if (sid1 > s && sid1 < cand) cand = sid1;
            if (sid2 > s && sid2 < cand) cand = sid2;
            if (sid3 > s && sid3 < cand) cand = sid3;
            const int nx = wave_min_u(cand);
            if (nx == 0x7fffffff) break;
            s = nx;
        }
    } else {
        // ---------------- tail rows (nrows % 64): per-row fp32 ----------------
        for (int r = r0; r < nrows; ++r) {
            const int s = __builtin_amdgcn_readfirstlane(segA[r]);
            const int j = __builtin_amdgcn_readfirstlane(inv[s]);
            const float* __restrict__ ap = A + (size_t)r * 64;
            const float* __restrict__ bp = B + (size_t)j * 4096 + lane;
            float a0 = 0.f, a1 = 0.f, a2 = 0.f, a3 = 0.f;
            #pragma unroll
            for (int k = 0; k < 64; k += 4) {
                a0 = fmaf(ap[k + 0], bp[(size_t)(k + 0) * 64], a0);
                a1 = fmaf(ap[k + 1], bp[(size_t)(k + 1) * 64], a1);
                a2 = fmaf(ap[k + 2], bp[(size_t)(k + 2) * 64], a2);
                a3 = fmaf(ap[k + 3], bp[(size_t)(k + 3) * 64], a3);
            }
            out[(size_t)r * 64 + lane] = (a0 + a1) + (a2 + a3);
        }
    }
}

extern "C" void kernel_launch(void* const* d_in, const int* in_sizes, int n_in,
                              void* d_out, int out_size, void* d_ws, size_t ws_size,
                              hipStream_t stream) {
    const float* A    = (const float*)d_in[0];
    const float* B    = (const float*)d_in[1];
    const int*   segA = (const int*)d_in[2];
    const int*   segB = (const int*)d_in[3];
    float*       out  = (float*)d_out;
    int*         inv  = (int*)d_ws;   // S ints of scratch

    const int K = 64;
    const int N = in_sizes[0] / K;    // 131072
    const int S = in_sizes[3];        // 128

    build_inv_kernel<<<(S + 127) / 128, 128, 0, stream>>>(segB, inv, S);

    int waves  = (N + RPW - 1) / RPW;          // 2048
    int blocks = (waves + WPB - 1) / WPB;      // 512
    segmm_mfma<<<blocks, 256, 0, stream>>>(A, B, segA, inv, out, N);
}